// Round 4
// baseline (838.521 us; speedup 1.0000x reference)
//
#include <hip/hip_runtime.h>
#include <hip/hip_bf16.h>
#include <stdint.h>

// Problem constants
#define Bn 2
#define Ln 2048
#define HIDn 1024
#define NHn 16
#define En 128
#define HSn 64

typedef unsigned short u16;
typedef short s16x8 __attribute__((ext_vector_type(8)));
typedef float f32x4 __attribute__((ext_vector_type(4)));
typedef float f32x16 __attribute__((ext_vector_type(16)));

__device__ __forceinline__ u16 f2bf(float f) {
  union { float f; uint32_t u; } v; v.f = f;
  uint32_t r = (v.u + 0x7fffu + ((v.u >> 16) & 1u)) >> 16;
  return (u16)r;
}
__device__ __forceinline__ float bf2f(u16 b) {
  union { uint32_t u; float f; } v; v.u = ((uint32_t)b) << 16;
  return v.f;
}
// async global->LDS, 16B per lane; lds dest = wave-uniform base + lane*16
__device__ __forceinline__ void async16(const void* g, void* l) {
  __builtin_amdgcn_global_load_lds((const __attribute__((address_space(1))) void*)g,
                                   (__attribute__((address_space(3))) void*)l, 16, 0, 0);
}

// ---------------- cast fp32 -> bf16 ----------------
__global__ void castbf(const float* __restrict__ in, u16* __restrict__ out, int n) {
  int i = (blockIdx.x * blockDim.x + threadIdx.x) * 4;
  if (i >= n) return;
  float4 v = *(const float4*)(in + i);
  u16 o[4] = {f2bf(v.x), f2bf(v.y), f2bf(v.z), f2bf(v.w)};
  *(uint64_t*)(out + i) = *(uint64_t*)o;
}

// ---------------- gate weight pre-sum ----------------
__global__ void wgprep(const float* __restrict__ Wg, float* __restrict__ wgu,
                       float* __restrict__ wgr) {
  int e = threadIdx.x;  // 128 threads
  wgu[e] = Wg[0 * 128 + e] + Wg[1 * 128 + e] + Wg[2 * 128 + e] + Wg[3 * 128 + e];
  wgr[e] = Wg[4 * 128 + e] + Wg[5 * 128 + e] + Wg[6 * 128 + e] + Wg[7 * 128 + e];
}

// ---------------- fused QKV GEMM (bf16 MFMA, 128x128 tile, BK=32) ----------------
// C[row, col] = A[row,:] . W[col,:]
// bx <  16 -> q (+bq), plain (B,NH,L,E)
// bx <  32 -> k, (B,NH,L,E) with e-granule XOR-swizzle by (l&15)
// bx >= 32 -> v (+bv), TRANSPOSED (B,NH,HS,L) with l-granule XOR-swizzle by (hs&7)
__global__ __launch_bounds__(256) void qkv_gemm(
    const u16* __restrict__ A, const u16* __restrict__ W,
    const float* __restrict__ bq, const float* __restrict__ bv,
    u16* __restrict__ qb, u16* __restrict__ kb, u16* __restrict__ vt) {
  __shared__ union {
    struct { u16 a[128 * 32]; u16 b[128 * 32]; } st;  // 16KB staging
    u16 cq[64][140];    // q/k epilogue: [l_local][e], pad->stride 140
    u16 cv[128][72];    // v  epilogue: [c_local][l_local], pad->stride 72
  } lds;
  const int tid = threadIdx.x, lane = tid & 63, w = tid >> 6;
  const int quad = lane >> 4, ln = lane & 15;
  const int bx = blockIdx.x, by = blockIdx.y;
  const int m0 = (w >> 1) * 64, n0 = (w & 1) * 64;
  f32x4 acc[4][4];
  for (int i = 0; i < 4; ++i)
    for (int j = 0; j < 4; ++j) acc[i][j] = (f32x4)0.0f;

  for (int k0 = 0; k0 < 1024; k0 += 32) {
    __syncthreads();
    for (int cc = 0; cc < 2; ++cc) {
      int c = w * 2 + cc;
      int row = c * 16 + (lane >> 2);
      int ke = (lane & 3) * 8;
      async16(A + (size_t)(by * 128 + row) * 1024 + k0 + ke, lds.st.a + c * 512);
      async16(W + (size_t)(bx * 128 + row) * 1024 + k0 + ke, lds.st.b + c * 512);
    }
    __syncthreads();
    s16x8 a[4], bf[4];
    for (int i = 0; i < 4; ++i)
      a[i] = *(const s16x8*)&lds.st.a[(m0 + i * 16 + ln) * 32 + quad * 8];
    for (int j = 0; j < 4; ++j)
      bf[j] = *(const s16x8*)&lds.st.b[(n0 + j * 16 + ln) * 32 + quad * 8];
    for (int i = 0; i < 4; ++i)
      for (int j = 0; j < 4; ++j)
        acc[i][j] = __builtin_amdgcn_mfma_f32_16x16x32_bf16(a[i], bf[j], acc[i][j], 0, 0, 0);
  }

  // per-lane bias for this wave's 4 column groups
  float bias[4];
#pragma unroll
  for (int j = 0; j < 4; ++j) {
    int col = bx * 128 + n0 + j * 16 + ln;
    bias[j] = (bx < 16) ? bq[col] : (bx >= 32 ? bv[col - 4096] : 0.0f);
  }

  if (bx < 32) {
    // ---- q/k epilogue: stage [l_local 0..63][e 0..127], store 64 rows x 16 segs
    for (int half = 0; half < 2; ++half) {
      __syncthreads();
      if ((w >> 1) == half) {
#pragma unroll
        for (int i = 0; i < 4; ++i)
#pragma unroll
          for (int j = 0; j < 4; ++j)
#pragma unroll
            for (int r = 0; r < 4; ++r)
              lds.cq[i * 16 + quad * 4 + r][n0 + j * 16 + ln] = f2bf(acc[i][j][r] + bias[j]);
      }
      __syncthreads();
#pragma unroll
      for (int it = 0; it < 4; ++it) {
        int slot = it * 256 + tid;        // 64 rows x 16 segs = 1024 slots
        int row = slot >> 4, seg = slot & 15;
        int rowg = by * 128 + half * 64 + row;
        int b = rowg >> 11, l = rowg & 2047;
        uint4 d = *(const uint4*)&lds.cq[row][seg * 8];
        if (bx < 16) {
          *(uint4*)(qb + ((size_t)(b * 16 + bx) * 2048 + l) * 128 + seg * 8) = d;
        } else {
          int sg = (seg ^ (l & 15)) & 15;
          *(uint4*)(kb + ((size_t)(b * 16 + (bx - 16)) * 2048 + l) * 128 + sg * 8) = d;
        }
      }
    }
  } else {
    // ---- v epilogue: stage transposed [c_local 0..127][l_local 0..63]
    for (int half = 0; half < 2; ++half) {
      __syncthreads();
      if ((w >> 1) == half) {
#pragma unroll
        for (int i = 0; i < 4; ++i)
#pragma unroll
          for (int j = 0; j < 4; ++j)
#pragma unroll
            for (int r = 0; r < 4; ++r)
              lds.cv[n0 + j * 16 + ln][i * 16 + quad * 4 + r] = f2bf(acc[i][j][r] + bias[j]);
      }
      __syncthreads();
      int rowg = by * 128 + half * 64;  // 64-aligned, same b for all 64 rows
      int b = rowg >> 11, lbase = rowg & 2047;
#pragma unroll
      for (int it = 0; it < 4; ++it) {
        int slot = it * 256 + tid;          // 128 rows x 8 segs
        int row = slot >> 3, seg = slot & 7;
        int c2 = (bx - 32) * 128 + row;
        int h = c2 >> 6, hs = c2 & 63;
        int sg = seg ^ (hs & 7);
        uint4 d = *(const uint4*)&lds.cv[row][seg * 8];
        *(uint4*)(vt + ((size_t)(b * 16 + h) * 64 + hs) * 2048 + lbase + sg * 8) = d;
      }
    }
  }
}

// ---------------- gate kernel (plain q layout) ----------------
__global__ void gate_kernel(const u16* __restrict__ qb, const float* __restrict__ wgu,
                            const float* __restrict__ wgr, const float* __restrict__ bg,
                            const float* __restrict__ eco, float* __restrict__ gate) {
  int t = blockIdx.x * 256 + threadIdx.x;  // 65536 rows = (b,h,l)
  int h = (t >> 11) & 15;
  const u16* q = qb + (size_t)t * 128;
  float u = bg[0] + bg[1] + bg[2] + bg[3];
  float rr = bg[4] + bg[5] + bg[6] + bg[7];
  for (int e = 0; e < 128; e += 8) {
    uint4 d = *(const uint4*)(q + e);
    const u16* p = (const u16*)&d;
#pragma unroll
    for (int jj = 0; jj < 8; ++jj) {
      float f = bf2f(p[jj]);
      u += f * wgu[e + jj];
      rr += f * wgr[e + jj];
    }
  }
  float gu = 1.0f / (1.0f + __expf(-u));
  float gr = 1.0f / (1.0f + __expf(-rr));
  gate[t] = gu * (gr * eco[h] - 1.0f) + 2.0f;
}

// ---------------- flash attention v4: counted-vmcnt pipeline ----------------
// Same math/layout as the passing v3-fixed kernel. New schedule: raw s_barrier
// + hand-counted s_waitcnt so K/V staging and rel_pos loads stay in flight a
// FULL tile across barriers (no vmcnt(0) drain per tile).
//
// VMEM issue order per iter kt (counts are per-thread, retire IN ORDER):
//   [after bar2]: rpwrite(ds) ; mask(kt+1) x1 ; rel_pos(kt+2) x8
//   [after bar3]: K/V stage(kt+2) x6 async16
// Waits:
//   bar2(kt): need rel_pos(kt+1) done. outstanding = m(kt+1)?0 + rp(kt+1)8 +
//             SKV(kt+1)6 = 14 -> vmcnt(6)
//   bar3(kt): need SKV(kt+1) done. outstanding = SKV(kt+1)6 + m(kt+2)1 +
//             rp(kt+2)8 = 15 -> vmcnt(9)   (tail: vmcnt(0))
// mask is 1 load/tile consumed via __shfl (lgkmcnt path - never pollutes the
// vmcnt stream; a late-issued vmem load would force a full in-order drain).
__global__ __launch_bounds__(256, 2) void attn_kernel(
    const u16* __restrict__ qb, const u16* __restrict__ kbp, const u16* __restrict__ vt,
    const float* __restrict__ mask, const float* __restrict__ relpos,
    const float* __restrict__ gate, float* __restrict__ out) {
  __shared__ u16 sK[2][64 * 128];    // [kr][e-granule ^ (kr&15)]
  __shared__ u16 sVt[2][64 * 64];    // [hs][k-granule ^ (hs&7)]
  __shared__ float sRP[128 * 64];    // [q][k-granule(4f) ^ (q&15)]

  const int tid = threadIdx.x, lane = tid & 63, w = tid >> 6;
  const int q5 = lane & 31, hi = lane >> 5;
  const int bx = blockIdx.x, h = blockIdx.y;
  const int qt = bx >> 1, b = bx & 1;
  const int q0 = qt * 128;
  const u16* qptr = qb + (size_t)(b * NHn + h) * Ln * En;
  const u16* kptr = kbp + (size_t)(b * NHn + h) * Ln * En;
  const u16* vptr = vt + (size_t)(b * NHn + h) * HSn * Ln;
  const float* rpb = relpos + (size_t)h * Ln * Ln + (size_t)q0 * Ln;
  const float* mk = mask + (size_t)b * Ln;
  const float* gt = gate + (size_t)(b * NHn + h) * Ln;

  // Q as B-operand frags: lane holds Q[q = q0+w*32+q5][e = es*16 + hi*8 + t]
  s16x8 aq[8];
  {
    const u16* qrow = qptr + (size_t)(q0 + w * 32 + q5) * En;
#pragma unroll
    for (int es = 0; es < 8; ++es)
      aq[es] = *(const s16x8*)(qrow + es * 16 + hi * 8);
  }
  const float gv = gt[q0 + w * 32 + q5];  // one gate per lane (own q-row)

  float l_part = 0.0f;
  f32x16 O0 = (f32x16)0.0f, O1 = (f32x16)0.0f;

  // stage K (64x128) + V^T (64x64) tile kt -> buf (verbatim; global pre-swizzled)
  auto stage = [&](int buf, int kt) {
    const int kbase = kt * 64;
#pragma unroll
    for (int cc = 0; cc < 4; ++cc) {
      int c = w * 4 + cc;  // 16 chunks of 1KB = 4 K-rows
      async16(kptr + (size_t)(kbase + c * 4 + (lane >> 4)) * En + (lane & 15) * 8,
              &sK[buf][c * 512]);
    }
#pragma unroll
    for (int cc = 0; cc < 2; ++cc) {
      int c = w * 2 + cc;  // 8 chunks of 1KB = 8 V-rows
      async16(vptr + (size_t)(c * 8 + (lane >> 3)) * Ln + kbase + (lane & 7) * 8,
              &sVt[buf][c * 512]);
    }
  };
  // coalesced rel_pos tile load: thread covers 8 float4 granules
  auto rpload = [&](int kt, float4 (&rg)[8]) {
#pragma unroll
    for (int i = 0; i < 8; ++i) {
      int s = i * 256 + tid;           // 128 rows x 16 granules
      int qq = s >> 4, gc = s & 15;
      rg[i] = *(const float4*)(rpb + (size_t)qq * Ln + kt * 64 + gc * 4);
    }
  };
  auto rpwrite = [&](const float4 (&rg)[8]) {
#pragma unroll
    for (int i = 0; i < 8; ++i) {
      int s = i * 256 + tid;
      int qq = s >> 4, gc = s & 15;
      *(float4*)&sRP[qq * 64 + ((gc ^ (qq & 15)) * 4)] = rg[i];
    }
  };

  const int NT = Ln / 64;  // 32
  // ---- prologue: m(0); rp(0); SKV(0); rpwrite; rp(1); SKV(1) ----
  float mcons = mk[lane];            // mask(0), 1 VMEM
  float4 rg[8];
  rpload(0, rg);                     // rp(0) x8
  stage(0, 0);                       // SKV(0) x6
  rpwrite(rg);                       // auto-waits m(0)+rp(0); SKV(0) stays in flight
  rpload(1, rg);                     // rp(1) x8
  stage(1, 1);                       // SKV(1) x6
  // outstanding: SKV(0)6 + rp(1)8 + SKV(1)6 = 20 -> retire SKV(0): vmcnt(14)
  asm volatile("s_waitcnt vmcnt(14) lgkmcnt(0)\n\ts_barrier" ::: "memory");

  for (int kt = 0; kt < NT; ++kt) {
    const int cur = kt & 1;

    // ---- S^T = K.Q^T : 2 k-blocks x 8 e-slices (A=K, B=Q) ----
    const u16* sKc = sK[cur];
    f32x16 S0 = (f32x16)0.0f, S1 = (f32x16)0.0f;
    __builtin_amdgcn_s_setprio(1);
#pragma unroll
    for (int es = 0; es < 8; ++es) {
      int gsw = ((es * 2 + hi) ^ (q5 & 15)) * 8;
      s16x8 ak0 = *(const s16x8*)&sKc[q5 * 128 + gsw];
      S0 = __builtin_amdgcn_mfma_f32_32x32x16_bf16(ak0, aq[es], S0, 0, 0, 0);
      s16x8 ak1 = *(const s16x8*)&sKc[(32 + q5) * 128 + gsw];
      S1 = __builtin_amdgcn_mfma_f32_32x32x16_bf16(ak1, aq[es], S1, 0, 0, 0);
    }
    __builtin_amdgcn_s_setprio(0);

    // ---- exp + pack to bf16 pairs (q = q5 lane-local; mask via shuffle) ----
    uint32_t pkv[16];
#pragma unroll
    for (int kbi = 0; kbi < 2; ++kbi) {
      const f32x16 Sa = kbi ? S1 : S0;
#pragma unroll
      for (int g = 0; g < 4; ++g) {
        f32x4 rp4 = *(const f32x4*)&sRP[(w * 32 + q5) * 64 +
                                        (((kbi * 8 + g * 2 + hi) ^ (q5 & 15)) * 4)];
        int mb = kbi * 32 + g * 8 + hi * 4;
        float m0 = __shfl(mcons, mb + 0, 64);
        float m1 = __shfl(mcons, mb + 1, 64);
        float m2 = __shfl(mcons, mb + 2, 64);
        float m3 = __shfl(mcons, mb + 3, 64);
        float p0 = __expf(fmaf(gv, rp4[0], fmaf(Sa[4 * g + 0], 0.125f, m0)));
        float p1 = __expf(fmaf(gv, rp4[1], fmaf(Sa[4 * g + 1], 0.125f, m1)));
        float p2 = __expf(fmaf(gv, rp4[2], fmaf(Sa[4 * g + 2], 0.125f, m2)));
        float p3 = __expf(fmaf(gv, rp4[3], fmaf(Sa[4 * g + 3], 0.125f, m3)));
        l_part += (p0 + p1) + (p2 + p3);
        uint32_t c0, c1;
        asm("v_cvt_pk_bf16_f32 %0, %1, %2" : "=v"(c0) : "v"(p0), "v"(p1));
        asm("v_cvt_pk_bf16_f32 %0, %1, %2" : "=v"(c1) : "v"(p2), "v"(p3));
        pkv[kbi * 8 + g * 2] = c0;
        pkv[kbi * 8 + g * 2 + 1] = c1;
      }
    }
    // cross-half exchange: lane gets its 8 consecutive k per 16-k PV slice.
#pragma unroll
    for (int base = 0; base < 16; base += 8) {
      asm volatile("v_permlane32_swap_b32 %0, %1" : "+v"(pkv[base + 0]), "+v"(pkv[base + 2]));
      asm volatile("v_permlane32_swap_b32 %0, %1" : "+v"(pkv[base + 1]), "+v"(pkv[base + 3]));
      asm volatile("v_permlane32_swap_b32 %0, %1" : "+v"(pkv[base + 4]), "+v"(pkv[base + 6]));
      asm volatile("v_permlane32_swap_b32 %0, %1" : "+v"(pkv[base + 5]), "+v"(pkv[base + 7]));
    }

    // bar2: rel_pos(kt+1) landed (vmcnt 14->6); all sRP(kt) reads drained
    asm volatile("s_waitcnt vmcnt(6) lgkmcnt(0)\n\ts_barrier" ::: "memory");
    if (kt + 1 < NT) rpwrite(rg);          // sRP <- rp(kt+1)
    if (kt + 2 < NT) {
      mcons = mk[(kt + 1) * 64 + lane];    // mask(kt+1) x1 (consumed next exp)
      rpload(kt + 2, rg);                  // rp(kt+2) x8
    } else if (kt + 1 < NT) {
      mcons = mk[(kt + 1) * 64 + lane];
    }

    // ---- O += P.V : 4 k-slices x 2 hs-blocks (A=P from regs, B=V^T) ----
    const u16* sVc = sVt[cur];
    __builtin_amdgcn_s_setprio(1);
#pragma unroll
    for (int ks2 = 0; ks2 < 4; ++ks2) {
      union { uint32_t u[4]; s16x8 v; } pu;
      pu.u[0] = pkv[ks2 * 4 + 0];
      pu.u[1] = pkv[ks2 * 4 + 1];
      pu.u[2] = pkv[ks2 * 4 + 2];
      pu.u[3] = pkv[ks2 * 4 + 3];
      s16x8 pa = pu.v;
      int gsw = ((ks2 * 2 + hi) ^ (q5 & 7)) * 8;
      s16x8 bv0 = *(const s16x8*)&sVc[q5 * 64 + gsw];
      O0 = __builtin_amdgcn_mfma_f32_32x32x16_bf16(pa, bv0, O0, 0, 0, 0);
      s16x8 bv1 = *(const s16x8*)&sVc[(32 + q5) * 64 + gsw];
      O1 = __builtin_amdgcn_mfma_f32_32x32x16_bf16(pa, bv1, O1, 0, 0, 0);
    }
    __builtin_amdgcn_s_setprio(0);

    // bar3: SKV(kt+1) landed; rpwrite published; buf[cur] free for restage
    if (kt + 2 < NT) {
      asm volatile("s_waitcnt vmcnt(9) lgkmcnt(0)\n\ts_barrier" ::: "memory");
      stage(cur, kt + 2);                  // SKV(kt+2) x6 -> buf[cur]
    } else {
      asm volatile("s_waitcnt vmcnt(0) lgkmcnt(0)\n\ts_barrier" ::: "memory");
    }
  }

  // ---- epilogue: l = own + partner half; 1/l distributed via shuffle ----
  float lt = l_part + __shfl_xor(l_part, 32, 64);
  float inv = 1.0f / lt;
#pragma unroll
  for (int i = 0; i < 16; ++i) {
    int qr = (i & 3) + 8 * (i >> 2) + 4 * hi;  // O row within 32-q block
    float iv = __shfl(inv, qr, 64);            // lane qr holds row qr's 1/l
    int qg = q0 + w * 32 + qr;
    float* orow = out + ((size_t)b * Ln + qg) * HIDn + h * 64;
    orow[q5] = O0[i] * iv;
    orow[32 + q5] = O1[i] * iv;
  }
}

extern "C" void kernel_launch(void* const* d_in, const int* in_sizes, int n_in,
                              void* d_out, int out_size, void* d_ws, size_t ws_size,
                              hipStream_t stream) {
  const float* hs = (const float*)d_in[0];
  const float* mask = (const float*)d_in[1];
  const float* relpos = (const float*)d_in[2];
  const float* Wq = (const float*)d_in[3];
  const float* bq = (const float*)d_in[4];
  const float* Wk = (const float*)d_in[5];
  const float* Wv = (const float*)d_in[6];
  const float* bv = (const float*)d_in[7];
  const float* Wg = (const float*)d_in[8];
  const float* bg = (const float*)d_in[9];
  const float* eco = (const float*)d_in[10];
  float* out = (float*)d_out;

  char* ws = (char*)d_ws;
  u16* hsb = (u16*)ws;                           // 8MB
  u16* wb = (u16*)(ws + (8ull << 20));           // 10MB
  u16* qb = (u16*)(ws + (18ull << 20));          // 16MB
  u16* kb = (u16*)(ws + (34ull << 20));          // 16MB
  u16* vt = (u16*)(ws + (50ull << 20));          // 8MB
  float* gate = (float*)(ws + (58ull << 20));    // 256KB
  float* wgu = (float*)(ws + (58ull << 20) + (1ull << 19));
  float* wgr = wgu + 128;

  castbf<<<4096, 256, 0, stream>>>(hs, hsb, 4096 * 1024);
  castbf<<<2048, 256, 0, stream>>>(Wq, wb, 2048 * 1024);
  castbf<<<2048, 256, 0, stream>>>(Wk, wb + 2048 * 1024, 2048 * 1024);
  castbf<<<1024, 256, 0, stream>>>(Wv, wb + 4096 * 1024, 1024 * 1024);
  wgprep<<<1, 128, 0, stream>>>(Wg, wgu, wgr);
  qkv_gemm<<<dim3(40, 32), 256, 0, stream>>>(hsb, wb, bq, bv, qb, kb, vt);
  gate_kernel<<<256, 256, 0, stream>>>(qb, wgu, wgr, bg, eco, gate);
  attn_kernel<<<dim3(32, 16), 256, 0, stream>>>(qb, kb, vt, mask, relpos, gate, out);
}

// Round 5
// 524.691 us; speedup vs baseline: 1.5981x; 1.5981x over previous
//
#include <hip/hip_runtime.h>
#include <hip/hip_bf16.h>
#include <stdint.h>

// Problem constants
#define Bn 2
#define Ln 2048
#define HIDn 1024
#define NHn 16
#define En 128
#define HSn 64

typedef unsigned short u16;
typedef short s16x8 __attribute__((ext_vector_type(8)));
typedef float f32x4 __attribute__((ext_vector_type(4)));
typedef float f32x16 __attribute__((ext_vector_type(16)));

__device__ __forceinline__ u16 f2bf(float f) {
  union { float f; uint32_t u; } v; v.f = f;
  uint32_t r = (v.u + 0x7fffu + ((v.u >> 16) & 1u)) >> 16;
  return (u16)r;
}
__device__ __forceinline__ float bf2f(u16 b) {
  union { uint32_t u; float f; } v; v.u = ((uint32_t)b) << 16;
  return v.f;
}
// async global->LDS, 16B per lane; lds dest = wave-uniform base + lane*16
__device__ __forceinline__ void async16(const void* g, void* l) {
  __builtin_amdgcn_global_load_lds((const __attribute__((address_space(1))) void*)g,
                                   (__attribute__((address_space(3))) void*)l, 16, 0, 0);
}

// ---------------- cast fp32 -> bf16 ----------------
__global__ void castbf(const float* __restrict__ in, u16* __restrict__ out, int n) {
  int i = (blockIdx.x * blockDim.x + threadIdx.x) * 4;
  if (i >= n) return;
  float4 v = *(const float4*)(in + i);
  u16 o[4] = {f2bf(v.x), f2bf(v.y), f2bf(v.z), f2bf(v.w)};
  *(uint64_t*)(out + i) = *(uint64_t*)o;
}

// ---------------- gate weight pre-sum ----------------
__global__ void wgprep(const float* __restrict__ Wg, float* __restrict__ wgu,
                       float* __restrict__ wgr) {
  int e = threadIdx.x;  // 128 threads
  wgu[e] = Wg[0 * 128 + e] + Wg[1 * 128 + e] + Wg[2 * 128 + e] + Wg[3 * 128 + e];
  wgr[e] = Wg[4 * 128 + e] + Wg[5 * 128 + e] + Wg[6 * 128 + e] + Wg[7 * 128 + e];
}

// ---------------- fused QKV GEMM (bf16 MFMA, 128x128 tile, BK=32) ----------------
// C[row, col] = A[row,:] . W[col,:]
// bx <  16 -> q (+bq), plain (B,NH,L,E)
// bx <  32 -> k, (B,NH,L,E) with e-granule XOR-swizzle by (l&15)
// bx >= 32 -> v (+bv), TRANSPOSED (B,NH,HS,L) with l-granule XOR-swizzle by (hs&7)
__global__ __launch_bounds__(256) void qkv_gemm(
    const u16* __restrict__ A, const u16* __restrict__ W,
    const float* __restrict__ bq, const float* __restrict__ bv,
    u16* __restrict__ qb, u16* __restrict__ kb, u16* __restrict__ vt) {
  __shared__ union {
    struct { u16 a[128 * 32]; u16 b[128 * 32]; } st;  // 16KB staging
    u16 cq[64][140];    // q/k epilogue: [l_local][e], pad->stride 140
    u16 cv[128][72];    // v  epilogue: [c_local][l_local], pad->stride 72
  } lds;
  const int tid = threadIdx.x, lane = tid & 63, w = tid >> 6;
  const int quad = lane >> 4, ln = lane & 15;
  const int bx = blockIdx.x, by = blockIdx.y;
  const int m0 = (w >> 1) * 64, n0 = (w & 1) * 64;
  f32x4 acc[4][4];
  for (int i = 0; i < 4; ++i)
    for (int j = 0; j < 4; ++j) acc[i][j] = (f32x4)0.0f;

  for (int k0 = 0; k0 < 1024; k0 += 32) {
    __syncthreads();
    for (int cc = 0; cc < 2; ++cc) {
      int c = w * 2 + cc;
      int row = c * 16 + (lane >> 2);
      int ke = (lane & 3) * 8;
      async16(A + (size_t)(by * 128 + row) * 1024 + k0 + ke, lds.st.a + c * 512);
      async16(W + (size_t)(bx * 128 + row) * 1024 + k0 + ke, lds.st.b + c * 512);
    }
    __syncthreads();
    s16x8 a[4], bf[4];
    for (int i = 0; i < 4; ++i)
      a[i] = *(const s16x8*)&lds.st.a[(m0 + i * 16 + ln) * 32 + quad * 8];
    for (int j = 0; j < 4; ++j)
      bf[j] = *(const s16x8*)&lds.st.b[(n0 + j * 16 + ln) * 32 + quad * 8];
    for (int i = 0; i < 4; ++i)
      for (int j = 0; j < 4; ++j)
        acc[i][j] = __builtin_amdgcn_mfma_f32_16x16x32_bf16(a[i], bf[j], acc[i][j], 0, 0, 0);
  }

  // per-lane bias for this wave's 4 column groups
  float bias[4];
#pragma unroll
  for (int j = 0; j < 4; ++j) {
    int col = bx * 128 + n0 + j * 16 + ln;
    bias[j] = (bx < 16) ? bq[col] : (bx >= 32 ? bv[col - 4096] : 0.0f);
  }

  if (bx < 32) {
    // ---- q/k epilogue: stage [l_local 0..63][e 0..127], store 64 rows x 16 segs
    for (int half = 0; half < 2; ++half) {
      __syncthreads();
      if ((w >> 1) == half) {
#pragma unroll
        for (int i = 0; i < 4; ++i)
#pragma unroll
          for (int j = 0; j < 4; ++j)
#pragma unroll
            for (int r = 0; r < 4; ++r)
              lds.cq[i * 16 + quad * 4 + r][n0 + j * 16 + ln] = f2bf(acc[i][j][r] + bias[j]);
      }
      __syncthreads();
#pragma unroll
      for (int it = 0; it < 4; ++it) {
        int slot = it * 256 + tid;        // 64 rows x 16 segs = 1024 slots
        int row = slot >> 4, seg = slot & 15;
        int rowg = by * 128 + half * 64 + row;
        int b = rowg >> 11, l = rowg & 2047;
        uint4 d = *(const uint4*)&lds.cq[row][seg * 8];
        if (bx < 16) {
          *(uint4*)(qb + ((size_t)(b * 16 + bx) * 2048 + l) * 128 + seg * 8) = d;
        } else {
          int sg = (seg ^ (l & 15)) & 15;
          *(uint4*)(kb + ((size_t)(b * 16 + (bx - 16)) * 2048 + l) * 128 + sg * 8) = d;
        }
      }
    }
  } else {
    // ---- v epilogue: stage transposed [c_local 0..127][l_local 0..63]
    for (int half = 0; half < 2; ++half) {
      __syncthreads();
      if ((w >> 1) == half) {
#pragma unroll
        for (int i = 0; i < 4; ++i)
#pragma unroll
          for (int j = 0; j < 4; ++j)
#pragma unroll
            for (int r = 0; r < 4; ++r)
              lds.cv[n0 + j * 16 + ln][i * 16 + quad * 4 + r] = f2bf(acc[i][j][r] + bias[j]);
      }
      __syncthreads();
      int rowg = by * 128 + half * 64;  // 64-aligned, same b for all 64 rows
      int b = rowg >> 11, lbase = rowg & 2047;
#pragma unroll
      for (int it = 0; it < 4; ++it) {
        int slot = it * 256 + tid;          // 128 rows x 8 segs
        int row = slot >> 3, seg = slot & 7;
        int c2 = (bx - 32) * 128 + row;
        int h = c2 >> 6, hs = c2 & 63;
        int sg = seg ^ (hs & 7);
        uint4 d = *(const uint4*)&lds.cv[row][seg * 8];
        *(uint4*)(vt + ((size_t)(b * 16 + h) * 64 + hs) * 2048 + lbase + sg * 8) = d;
      }
    }
  }
}

// ---------------- gate kernel (plain q layout) ----------------
__global__ void gate_kernel(const u16* __restrict__ qb, const float* __restrict__ wgu,
                            const float* __restrict__ wgr, const float* __restrict__ bg,
                            const float* __restrict__ eco, float* __restrict__ gate) {
  int t = blockIdx.x * 256 + threadIdx.x;  // 65536 rows = (b,h,l)
  int h = (t >> 11) & 15;
  const u16* q = qb + (size_t)t * 128;
  float u = bg[0] + bg[1] + bg[2] + bg[3];
  float rr = bg[4] + bg[5] + bg[6] + bg[7];
  for (int e = 0; e < 128; e += 8) {
    uint4 d = *(const uint4*)(q + e);
    const u16* p = (const u16*)&d;
#pragma unroll
    for (int jj = 0; jj < 8; ++jj) {
      float f = bf2f(p[jj]);
      u += f * wgu[e + jj];
      rr += f * wgr[e + jj];
    }
  }
  float gu = 1.0f / (1.0f + __expf(-u));
  float gr = 1.0f / (1.0f + __expf(-rr));
  gate[t] = gu * (gr * eco[h] - 1.0f) + 2.0f;
}

// ---------------- flash attention v5: all-async counted-vmcnt pipeline ----------------
// Same math/layouts as the passing R3 kernel. ALL tile streams (K, V^T, rel_pos) go
// through global_load_lds -> one in-order vmcnt queue, zero prefetch registers.
// sRP is WAVE-PRIVATE (wave w stages+reads only rows [32w,32w+32)) -> no barrier,
// no ds_write, single-buffered. One barrier per tile (K/V buf swap).
//
// Per-thread VMEM issue order (uniform every iter via tail clamping):
//   preamble: aq x8 + gv x1 = 9
//   prologue: m(0) 1; rp(0) 8; SKV(0) 6; SKV(1) 6   -> wait vmcnt(6) [leaves SKV(1)]
//   iter kt:  QK | wait vmcnt(6) [retires rp(kt)+m(kt), leaves SKV(kt+1)] | exp
//             issue rp(kt+1) 8 + m(kt+1) 1 | permlane+PV
//             wait vmcnt(9) lgkmcnt(0) [retires SKV(kt+1)] + s_barrier
//             issue SKV(kt+2) 6 into freed buf
__global__ __launch_bounds__(256, 2) void attn_kernel(
    const u16* __restrict__ qb, const u16* __restrict__ kbp, const u16* __restrict__ vt,
    const float* __restrict__ mask, const float* __restrict__ relpos,
    const float* __restrict__ gate, float* __restrict__ out) {
  __shared__ u16 sK[2][64 * 128];    // [kr][e-granule ^ (kr&15)]
  __shared__ u16 sVt[2][64 * 64];    // [hs][k-granule ^ (hs&7)]
  __shared__ float sRP[128 * 64];    // [q][k-granule(4f) ^ (q&15)], wave-private rows

  const int tid = threadIdx.x, lane = tid & 63, w = tid >> 6;
  const int q5 = lane & 31, hi = lane >> 5;
  const int bx = blockIdx.x, h = blockIdx.y;
  const int qt = bx >> 1, b = bx & 1;
  const int q0 = qt * 128;
  const u16* qptr = qb + (size_t)(b * NHn + h) * Ln * En;
  const u16* kptr = kbp + (size_t)(b * NHn + h) * Ln * En;
  const u16* vptr = vt + (size_t)(b * NHn + h) * HSn * Ln;
  const float* rpb = relpos + (size_t)h * Ln * Ln + (size_t)q0 * Ln;
  const float* mk = mask + (size_t)b * Ln;
  const float* gt = gate + (size_t)(b * NHn + h) * Ln;

  // Q as B-operand frags: lane holds Q[q = q0+w*32+q5][e = es*16 + hi*8 + t]
  s16x8 aq[8];
  {
    const u16* qrow = qptr + (size_t)(q0 + w * 32 + q5) * En;
#pragma unroll
    for (int es = 0; es < 8; ++es)
      aq[es] = *(const s16x8*)(qrow + es * 16 + hi * 8);
  }
  const float gv = gt[q0 + w * 32 + q5];  // one gate per lane (own q-row)

  float l_part = 0.0f;
  f32x16 O0 = (f32x16)0.0f, O1 = (f32x16)0.0f;

  // stage K (64x128) + V^T (64x64) tile kt -> buf (verbatim; global pre-swizzled): 6 VMEM
  auto stage = [&](int buf, int kt) {
    const int kbase = kt * 64;
#pragma unroll
    for (int cc = 0; cc < 4; ++cc) {
      int c = w * 4 + cc;  // 16 chunks of 1KB = 4 K-rows
      async16(kptr + (size_t)(kbase + c * 4 + (lane >> 4)) * En + (lane & 15) * 8,
              &sK[buf][c * 512]);
    }
#pragma unroll
    for (int cc = 0; cc < 2; ++cc) {
      int c = w * 2 + cc;  // 8 chunks of 1KB = 8 V-rows
      async16(vptr + (size_t)(c * 8 + (lane >> 3)) * Ln + kbase + (lane & 7) * 8,
              &sVt[buf][c * 512]);
    }
  };
  // stage rel_pos tile kt -> sRP, wave-private rows [32w,32w+32): 8 VMEM.
  // LDS[row][G] must hold rp[row][G ^ (row&15)] -> pre-swizzle the GLOBAL granule.
  auto rpstage = [&](int kt) {
    const int r_lo = lane >> 4;            // row within 4-row chunk
    const int Gl = lane & 15;              // lds granule this lane fills
#pragma unroll
    for (int cc = 0; cc < 8; ++cc) {
      int row = w * 32 + cc * 4 + r_lo;    // global q-row in tile (wave-private)
      int gg = Gl ^ (row & 15);            // source granule (inverse==same XOR)
      async16(rpb + (size_t)row * Ln + kt * 64 + gg * 4,
              (char*)sRP + w * 8192 + cc * 1024);
    }
  };

  const int NT = Ln / 64;  // 32
  // ---- prologue ----
  float mcons = mk[lane];                  // mask(0): 1 VMEM
  rpstage(0);                              // 8 VMEM
  stage(0, 0);                             // 6 VMEM
  stage(1, 1);                             // 6 VMEM
  // queue: [preamble 9, m 1, rp 8, SKV(0) 6, SKV(1) 6] -> retire through SKV(0)
  asm volatile("s_waitcnt vmcnt(6) lgkmcnt(0)\n\ts_barrier" ::: "memory");

  float mnext;
#pragma unroll 1
  for (int kt = 0; kt < NT; ++kt) {
    const int cur = kt & 1;

    // ---- S^T = K.Q^T : 2 k-blocks x 8 e-slices (A=K, B=Q) ----
    const u16* sKc = sK[cur];
    f32x16 S0 = (f32x16)0.0f, S1 = (f32x16)0.0f;
    __builtin_amdgcn_s_setprio(1);
#pragma unroll
    for (int es = 0; es < 8; ++es) {
      int gsw = ((es * 2 + hi) ^ (q5 & 15)) * 8;
      s16x8 ak0 = *(const s16x8*)&sKc[q5 * 128 + gsw];
      S0 = __builtin_amdgcn_mfma_f32_32x32x16_bf16(ak0, aq[es], S0, 0, 0, 0);
      s16x8 ak1 = *(const s16x8*)&sKc[(32 + q5) * 128 + gsw];
      S1 = __builtin_amdgcn_mfma_f32_32x32x16_bf16(ak1, aq[es], S1, 0, 0, 0);
    }
    __builtin_amdgcn_s_setprio(0);

    // rp(kt) + mask(kt) landed: retire them, keep SKV(kt+1) in flight
    asm volatile("s_waitcnt vmcnt(6)" ::: "memory");
    __builtin_amdgcn_sched_barrier(0);

    // ---- exp + pack to bf16 pairs (q = q5 lane-local; mask via shuffle) ----
    uint32_t pkv[16];
#pragma unroll
    for (int kbi = 0; kbi < 2; ++kbi) {
      const f32x16 Sa = kbi ? S1 : S0;
#pragma unroll
      for (int g = 0; g < 4; ++g) {
        f32x4 rp4 = *(const f32x4*)&sRP[(w * 32 + q5) * 64 +
                                        (((kbi * 8 + g * 2 + hi) ^ (q5 & 15)) * 4)];
        int mb = kbi * 32 + g * 8 + hi * 4;
        float m0 = __shfl(mcons, mb + 0, 64);
        float m1 = __shfl(mcons, mb + 1, 64);
        float m2 = __shfl(mcons, mb + 2, 64);
        float m3 = __shfl(mcons, mb + 3, 64);
        float p0 = __expf(fmaf(gv, rp4[0], fmaf(Sa[4 * g + 0], 0.125f, m0)));
        float p1 = __expf(fmaf(gv, rp4[1], fmaf(Sa[4 * g + 1], 0.125f, m1)));
        float p2 = __expf(fmaf(gv, rp4[2], fmaf(Sa[4 * g + 2], 0.125f, m2)));
        float p3 = __expf(fmaf(gv, rp4[3], fmaf(Sa[4 * g + 3], 0.125f, m3)));
        l_part += (p0 + p1) + (p2 + p3);
        uint32_t c0, c1;
        asm("v_cvt_pk_bf16_f32 %0, %1, %2" : "=v"(c0) : "v"(p0), "v"(p1));
        asm("v_cvt_pk_bf16_f32 %0, %1, %2" : "=v"(c1) : "v"(p2), "v"(p3));
        pkv[kbi * 8 + g * 2] = c0;
        pkv[kbi * 8 + g * 2 + 1] = c1;
      }
    }

    // exp's sRP reads are consumed; safe to overwrite own rows with rp(kt+1).
    // Uniform counts: clamp tail indices (dummy re-stage of last tile, unread).
    __builtin_amdgcn_sched_barrier(0);
    {
      int nk = kt + 1 < NT ? kt + 1 : NT - 1;
      rpstage(nk);                              // 8 VMEM
      mnext = mk[nk * 64 + lane];               // 1 VMEM
    }

    // cross-half exchange: lane gets its 8 consecutive k per 16-k PV slice.
#pragma unroll
    for (int base = 0; base < 16; base += 8) {
      asm volatile("v_permlane32_swap_b32 %0, %1" : "+v"(pkv[base + 0]), "+v"(pkv[base + 2]));
      asm volatile("v_permlane32_swap_b32 %0, %1" : "+v"(pkv[base + 1]), "+v"(pkv[base + 3]));
      asm volatile("v_permlane32_swap_b32 %0, %1" : "+v"(pkv[base + 4]), "+v"(pkv[base + 6]));
      asm volatile("v_permlane32_swap_b32 %0, %1" : "+v"(pkv[base + 5]), "+v"(pkv[base + 7]));
    }

    // ---- O += P.V : 4 k-slices x 2 hs-blocks (A=P from regs, B=V^T) ----
    const u16* sVc = sVt[cur];
    __builtin_amdgcn_s_setprio(1);
#pragma unroll
    for (int ks2 = 0; ks2 < 4; ++ks2) {
      union { uint32_t u[4]; s16x8 v; } pu;
      pu.u[0] = pkv[ks2 * 4 + 0];
      pu.u[1] = pkv[ks2 * 4 + 1];
      pu.u[2] = pkv[ks2 * 4 + 2];
      pu.u[3] = pkv[ks2 * 4 + 3];
      s16x8 pa = pu.v;
      int gsw = ((ks2 * 2 + hi) ^ (q5 & 7)) * 8;
      s16x8 bv0 = *(const s16x8*)&sVc[q5 * 64 + gsw];
      O0 = __builtin_amdgcn_mfma_f32_32x32x16_bf16(pa, bv0, O0, 0, 0, 0);
      s16x8 bv1 = *(const s16x8*)&sVc[(32 + q5) * 64 + gsw];
      O1 = __builtin_amdgcn_mfma_f32_32x32x16_bf16(pa, bv1, O1, 0, 0, 0);
    }
    __builtin_amdgcn_s_setprio(0);
    mcons = mnext;

    // SKV(kt+1) landed; all waves' LDS reads of buf[cur] drained -> restage it
    asm volatile("s_waitcnt vmcnt(9) lgkmcnt(0)\n\ts_barrier" ::: "memory");
    {
      int nk2 = kt + 2 < NT ? kt + 2 : NT - 1;
      stage(cur, nk2);                          // 6 VMEM (dummy on last 2 iters)
    }
  }
  asm volatile("s_waitcnt vmcnt(0) lgkmcnt(0)" ::: "memory");

  // ---- epilogue: l = own + partner half; 1/l distributed via shuffle ----
  float lt = l_part + __shfl_xor(l_part, 32, 64);
  float inv = 1.0f / lt;
#pragma unroll
  for (int i = 0; i < 16; ++i) {
    int qr = (i & 3) + 8 * (i >> 2) + 4 * hi;  // O row within 32-q block
    float iv = __shfl(inv, qr, 64);            // lane qr holds row qr's 1/l
    int qg = q0 + w * 32 + qr;
    float* orow = out + ((size_t)b * Ln + qg) * HIDn + h * 64;
    orow[q5] = O0[i] * iv;
    orow[32 + q5] = O1[i] * iv;
  }
}

extern "C" void kernel_launch(void* const* d_in, const int* in_sizes, int n_in,
                              void* d_out, int out_size, void* d_ws, size_t ws_size,
                              hipStream_t stream) {
  const float* hs = (const float*)d_in[0];
  const float* mask = (const float*)d_in[1];
  const float* relpos = (const float*)d_in[2];
  const float* Wq = (const float*)d_in[3];
  const float* bq = (const float*)d_in[4];
  const float* Wk = (const float*)d_in[5];
  const float* Wv = (const float*)d_in[6];
  const float* bv = (const float*)d_in[7];
  const float* Wg = (const float*)d_in[8];
  const float* bg = (const float*)d_in[9];
  const float* eco = (const float*)d_in[10];
  float* out = (float*)d_out;

  char* ws = (char*)d_ws;
  u16* hsb = (u16*)ws;                           // 8MB
  u16* wb = (u16*)(ws + (8ull << 20));           // 10MB
  u16* qb = (u16*)(ws + (18ull << 20));          // 16MB
  u16* kb = (u16*)(ws + (34ull << 20));          // 16MB
  u16* vt = (u16*)(ws + (50ull << 20));          // 8MB
  float* gate = (float*)(ws + (58ull << 20));    // 256KB
  float* wgu = (float*)(ws + (58ull << 20) + (1ull << 19));
  float* wgr = wgu + 128;

  castbf<<<4096, 256, 0, stream>>>(hs, hsb, 4096 * 1024);
  castbf<<<2048, 256, 0, stream>>>(Wq, wb, 2048 * 1024);
  castbf<<<2048, 256, 0, stream>>>(Wk, wb + 2048 * 1024, 2048 * 1024);
  castbf<<<1024, 256, 0, stream>>>(Wv, wb + 4096 * 1024, 1024 * 1024);
  wgprep<<<1, 128, 0, stream>>>(Wg, wgu, wgr);
  qkv_gemm<<<dim3(40, 32), 256, 0, stream>>>(hsb, wb, bq, bv, qb, kb, vt);
  gate_kernel<<<256, 256, 0, stream>>>(qb, wgu, wgr, bg, eco, gate);
  attn_kernel<<<dim3(32, 16), 256, 0, stream>>>(qb, kb, vt, mask, relpos, gate, out);
}